// Round 1
// baseline (1425.509 us; speedup 1.0000x reference)
//
#include <hip/hip_runtime.h>
#include <math.h>

// Problem constants (fixed by setup_inputs)
#define BATCH  4
#define SEQ    2048
#define DIMK   2048
#define NHEADS 16
#define DH     128

static constexpr float SCALE = 0.088388347648318447f; // 1/sqrt(128)
static constexpr float EPS_N = 1e-12f;

// ---------------------------------------------------------------------------
// Kernel 1: K/V projection.  Y = ctx @ W^T + bias   (M=8192, N=128, K=2048)
// grid (128, 2): blockIdx.y==0 -> K, ==1 -> V.  256 thr, tile 64x128, BK=16.
// ---------------------------------------------------------------------------
__global__ __launch_bounds__(256)
void kv_proj_kernel(const float* __restrict__ ctx,
                    const float* __restrict__ Wk, const float* __restrict__ bk,
                    const float* __restrict__ Wv, const float* __restrict__ bv,
                    float* __restrict__ kraw, float* __restrict__ vraw)
{
    __shared__ float As[16][72];   // [k][m], stride 72 floats (288B, 16B-aligned)
    __shared__ float Bs[16][136];  // [k][n], stride 136 floats (544B, 16B-aligned)

    const int tid = threadIdx.x;
    const int tx = tid & 15, ty = tid >> 4;
    const int m0 = blockIdx.x * 64;

    const float* __restrict__ W    = blockIdx.y ? Wv : Wk;
    const float* __restrict__ bias = blockIdx.y ? bv : bk;
    float* __restrict__ Y          = blockIdx.y ? vraw : kraw;

    const int arow = tid >> 2, ak4 = (tid & 3) << 2;  // A stage: 64 rows x 16 k
    const int brow = tid >> 1, bk8 = (tid & 1) << 3;  // B stage: 128 rows x 16 k

    float acc[4][8];
#pragma unroll
    for (int i = 0; i < 4; ++i)
#pragma unroll
        for (int j = 0; j < 8; ++j) acc[i][j] = 0.f;

    for (int k0 = 0; k0 < DIMK; k0 += 16) {
        float4 av = *(const float4*)&ctx[(size_t)(m0 + arow) * DIMK + k0 + ak4];
        As[ak4 + 0][arow] = av.x; As[ak4 + 1][arow] = av.y;
        As[ak4 + 2][arow] = av.z; As[ak4 + 3][arow] = av.w;

        float4 b0 = *(const float4*)&W[(size_t)brow * DIMK + k0 + bk8];
        float4 b1 = *(const float4*)&W[(size_t)brow * DIMK + k0 + bk8 + 4];
        Bs[bk8 + 0][brow] = b0.x; Bs[bk8 + 1][brow] = b0.y;
        Bs[bk8 + 2][brow] = b0.z; Bs[bk8 + 3][brow] = b0.w;
        Bs[bk8 + 4][brow] = b1.x; Bs[bk8 + 5][brow] = b1.y;
        Bs[bk8 + 6][brow] = b1.z; Bs[bk8 + 7][brow] = b1.w;
        __syncthreads();

#pragma unroll
        for (int k = 0; k < 16; ++k) {
            float4 a  = *(const float4*)&As[k][ty * 4];
            float4 p  = *(const float4*)&Bs[k][tx * 8];
            float4 q4 = *(const float4*)&Bs[k][tx * 8 + 4];
            float avals[4] = {a.x, a.y, a.z, a.w};
            float bvals[8] = {p.x, p.y, p.z, p.w, q4.x, q4.y, q4.z, q4.w};
#pragma unroll
            for (int i = 0; i < 4; ++i)
#pragma unroll
                for (int j = 0; j < 8; ++j)
                    acc[i][j] = fmaf(avals[i], bvals[j], acc[i][j]);
        }
        __syncthreads();
    }

    float bb[8];
#pragma unroll
    for (int j = 0; j < 8; ++j) bb[j] = bias[tx * 8 + j];

#pragma unroll
    for (int i = 0; i < 4; ++i) {
        const int r = m0 + ty * 4 + i;
        float4 o0, o1;
        o0.x = acc[i][0] + bb[0]; o0.y = acc[i][1] + bb[1];
        o0.z = acc[i][2] + bb[2]; o0.w = acc[i][3] + bb[3];
        o1.x = acc[i][4] + bb[4]; o1.y = acc[i][5] + bb[5];
        o1.z = acc[i][6] + bb[6]; o1.w = acc[i][7] + bb[7];
        *(float4*)&Y[(size_t)r * DH + tx * 8]     = o0;
        *(float4*)&Y[(size_t)r * DH + tx * 8 + 4] = o1;
    }
}

// ---------------------------------------------------------------------------
// Kernel 2: partial kv = sum_m k_norm[m] (outer) v[m]  per batch, 16 chunks.
// grid 64 = 4 batches x 16 chunks (128 seq rows each). 256 threads.
// ---------------------------------------------------------------------------
__global__ __launch_bounds__(256)
void kv_outer_kernel(const float* __restrict__ kraw,
                     const float* __restrict__ vraw,
                     float* __restrict__ partials)
{
    __shared__ float invn[128];
    __shared__ float kbuf[8][128];
    __shared__ float vbuf[8][128];

    const int tid = threadIdx.x;
    const int bx  = blockIdx.x;
    const int g0  = (bx >> 4) * SEQ + (bx & 15) * 128;

    // row inverse norms (2 threads per row)
    {
        const int m = tid >> 1, half = tid & 1;
        const float* row = &kraw[(size_t)(g0 + m) * DH + half * 64];
        float s = 0.f;
#pragma unroll
        for (int j = 0; j < 64; j += 4) {
            float4 t4 = *(const float4*)&row[j];
            s += t4.x * t4.x + t4.y * t4.y + t4.z * t4.z + t4.w * t4.w;
        }
        s += __shfl_xor(s, 1);
        if (!half) invn[m] = 1.0f / fmaxf(sqrtf(s), EPS_N);
    }
    __syncthreads();

    const int d1 = tid >> 1;
    const int d2b = (tid & 1) * 64;
    float4 acc[16];
#pragma unroll
    for (int j = 0; j < 16; ++j) acc[j] = make_float4(0.f, 0.f, 0.f, 0.f);

    for (int mc = 0; mc < 128; mc += 8) {
        const int lr = tid >> 5;          // 0..7
        const int lc = (tid & 31) * 4;    // 0..124
        float4 kk = *(const float4*)&kraw[(size_t)(g0 + mc + lr) * DH + lc];
        const float sc = invn[mc + lr];
        kk.x *= sc; kk.y *= sc; kk.z *= sc; kk.w *= sc;
        *(float4*)&kbuf[lr][lc] = kk;
        float4 vv = *(const float4*)&vraw[(size_t)(g0 + mc + lr) * DH + lc];
        *(float4*)&vbuf[lr][lc] = vv;
        __syncthreads();

#pragma unroll
        for (int mm = 0; mm < 8; ++mm) {
            const float kn = kbuf[mm][d1];
#pragma unroll
            for (int j = 0; j < 16; ++j) {
                float4 v4 = *(const float4*)&vbuf[mm][d2b + j * 4];
                acc[j].x = fmaf(kn, v4.x, acc[j].x);
                acc[j].y = fmaf(kn, v4.y, acc[j].y);
                acc[j].z = fmaf(kn, v4.z, acc[j].z);
                acc[j].w = fmaf(kn, v4.w, acc[j].w);
            }
        }
        __syncthreads();
    }

    float* p = &partials[(size_t)bx * 16384 + (size_t)d1 * 128 + d2b];
#pragma unroll
    for (int j = 0; j < 16; ++j) *(float4*)&p[j * 4] = acc[j];
}

// ---------------------------------------------------------------------------
// Kernel 3: reduce 16 chunk-partials per batch -> kv (scale folded in).
// ---------------------------------------------------------------------------
__global__ __launch_bounds__(256)
void kv_reduce_kernel(const float* __restrict__ partials, float* __restrict__ kvg)
{
    const int i = blockIdx.x * 256 + threadIdx.x;  // 0..65535
    const int b = i >> 14;
    const int e = i & 16383;
    float s = 0.f;
#pragma unroll
    for (int c = 0; c < 16; ++c)
        s += partials[(size_t)(b * 16 + c) * 16384 + e];
    kvg[i] = s * SCALE;
}

// ---------------------------------------------------------------------------
// Kernel 4: Q projection GEMM (M=8192, N=2048, K=2048) fused with per-head
// L2-normalize and x kv[b] epilogue.  grid (128 Mtiles, 16 heads), 256 thr.
// ---------------------------------------------------------------------------
__global__ __launch_bounds__(256)
void q_out_kernel(const float* __restrict__ x,
                  const float* __restrict__ Wq, const float* __restrict__ bq,
                  const float* __restrict__ kvg, float* __restrict__ out)
{
    __shared__ float As[16][72];
    __shared__ float Bs[16][136];
    __shared__ float qs[64][136];

    const int tid = threadIdx.x;
    const int tx = tid & 15, ty = tid >> 4;
    const int m0 = blockIdx.x * 64;
    const int h  = blockIdx.y;
    const int n0 = h * DH;

    const int arow = tid >> 2, ak4 = (tid & 3) << 2;
    const int brow = tid >> 1, bk8 = (tid & 1) << 3;

    float acc[4][8];
#pragma unroll
    for (int i = 0; i < 4; ++i)
#pragma unroll
        for (int j = 0; j < 8; ++j) acc[i][j] = 0.f;

    for (int k0 = 0; k0 < DIMK; k0 += 16) {
        float4 av = *(const float4*)&x[(size_t)(m0 + arow) * DIMK + k0 + ak4];
        As[ak4 + 0][arow] = av.x; As[ak4 + 1][arow] = av.y;
        As[ak4 + 2][arow] = av.z; As[ak4 + 3][arow] = av.w;

        float4 b0 = *(const float4*)&Wq[(size_t)(n0 + brow) * DIMK + k0 + bk8];
        float4 b1 = *(const float4*)&Wq[(size_t)(n0 + brow) * DIMK + k0 + bk8 + 4];
        Bs[bk8 + 0][brow] = b0.x; Bs[bk8 + 1][brow] = b0.y;
        Bs[bk8 + 2][brow] = b0.z; Bs[bk8 + 3][brow] = b0.w;
        Bs[bk8 + 4][brow] = b1.x; Bs[bk8 + 5][brow] = b1.y;
        Bs[bk8 + 6][brow] = b1.z; Bs[bk8 + 7][brow] = b1.w;
        __syncthreads();

#pragma unroll
        for (int k = 0; k < 16; ++k) {
            float4 a  = *(const float4*)&As[k][ty * 4];
            float4 p  = *(const float4*)&Bs[k][tx * 8];
            float4 q4 = *(const float4*)&Bs[k][tx * 8 + 4];
            float avals[4] = {a.x, a.y, a.z, a.w};
            float bvals[8] = {p.x, p.y, p.z, p.w, q4.x, q4.y, q4.z, q4.w};
#pragma unroll
            for (int i = 0; i < 4; ++i)
#pragma unroll
                for (int j = 0; j < 8; ++j)
                    acc[i][j] = fmaf(avals[i], bvals[j], acc[i][j]);
        }
        __syncthreads();
    }

    // bias + per-row L2 normalize (reduce across the 16 tx lanes of each ty)
    float bb[8];
#pragma unroll
    for (int j = 0; j < 8; ++j) bb[j] = bq[n0 + tx * 8 + j];

    float inv[4];
#pragma unroll
    for (int i = 0; i < 4; ++i) {
        float s = 0.f;
#pragma unroll
        for (int j = 0; j < 8; ++j) {
            acc[i][j] += bb[j];
            s += acc[i][j] * acc[i][j];
        }
        s += __shfl_xor(s, 1);
        s += __shfl_xor(s, 2);
        s += __shfl_xor(s, 4);
        s += __shfl_xor(s, 8);
        inv[i] = 1.0f / fmaxf(sqrtf(s), EPS_N);
    }

#pragma unroll
    for (int i = 0; i < 4; ++i)
#pragma unroll
        for (int j = 0; j < 8; ++j)
            qs[ty * 4 + i][tx * 8 + j] = acc[i][j] * inv[i];
    __syncthreads();

    // epilogue: out_tile = q_norm (64x128) @ kv_b (128x128), kv staged via Bs
    const int b = m0 / SEQ;
    const float* __restrict__ kvb = kvg + (size_t)b * DH * DH;

    float acc2[4][8];
#pragma unroll
    for (int i = 0; i < 4; ++i)
#pragma unroll
        for (int j = 0; j < 8; ++j) acc2[i][j] = 0.f;

    for (int dt = 0; dt < DH; dt += 16) {
        const int drow = tid >> 4;         // 0..15
        const int dcol = (tid & 15) * 8;   // 0..120
        float4 c0 = *(const float4*)&kvb[(size_t)(dt + drow) * DH + dcol];
        float4 c1 = *(const float4*)&kvb[(size_t)(dt + drow) * DH + dcol + 4];
        __syncthreads();  // Bs free (last read finished before this point)
        *(float4*)&Bs[drow][dcol]     = c0;
        *(float4*)&Bs[drow][dcol + 4] = c1;
        __syncthreads();

#pragma unroll
        for (int d = 0; d < 16; ++d) {
            float qv[4];
#pragma unroll
            for (int i = 0; i < 4; ++i) qv[i] = qs[ty * 4 + i][dt + d];
            float4 p  = *(const float4*)&Bs[d][tx * 8];
            float4 q4 = *(const float4*)&Bs[d][tx * 8 + 4];
            float bvals[8] = {p.x, p.y, p.z, p.w, q4.x, q4.y, q4.z, q4.w};
#pragma unroll
            for (int i = 0; i < 4; ++i)
#pragma unroll
                for (int j = 0; j < 8; ++j)
                    acc2[i][j] = fmaf(qv[i], bvals[j], acc2[i][j]);
        }
    }

    // write out[b][h][iseq][c]
#pragma unroll
    for (int i = 0; i < 4; ++i) {
        const int r    = m0 + ty * 4 + i;
        const int iseq = r - b * SEQ;
        float4 o0, o1;
        o0.x = acc2[i][0]; o0.y = acc2[i][1]; o0.z = acc2[i][2]; o0.w = acc2[i][3];
        o1.x = acc2[i][4]; o1.y = acc2[i][5]; o1.z = acc2[i][6]; o1.w = acc2[i][7];
        const size_t obase = (((size_t)b * NHEADS + h) * SEQ + iseq) * DH + tx * 8;
        *(float4*)&out[obase]     = o0;
        *(float4*)&out[obase + 4] = o1;
    }
}

// ---------------------------------------------------------------------------
extern "C" void kernel_launch(void* const* d_in, const int* in_sizes, int n_in,
                              void* d_out, int out_size, void* d_ws, size_t ws_size,
                              hipStream_t stream)
{
    const float* x   = (const float*)d_in[0];
    const float* ctx = (const float*)d_in[1];
    const float* Wq  = (const float*)d_in[2];
    const float* bq  = (const float*)d_in[3];
    const float* Wk  = (const float*)d_in[4];
    const float* bk  = (const float*)d_in[5];
    const float* Wv  = (const float*)d_in[6];
    const float* bv  = (const float*)d_in[7];

    float* out      = (float*)d_out;
    // scratch carved out of d_out's tail-unused region (out is 16.7M floats;
    // all of it is rewritten by q_out_kernel at the end):
    float* kraw     = out;              // 1,048,576 floats
    float* vraw     = out + 1048576;    // 1,048,576 floats
    float* partials = out + 2097152;    // 1,048,576 floats (64 x 16384)
    float* kvg      = (float*)d_ws;     // 65,536 floats (256 KB)

    kv_proj_kernel<<<dim3(128, 2), 256, 0, stream>>>(ctx, Wk, bk, Wv, bv, kraw, vraw);
    kv_outer_kernel<<<64, 256, 0, stream>>>(kraw, vraw, partials);
    kv_reduce_kernel<<<256, 256, 0, stream>>>(partials, kvg);
    q_out_kernel<<<dim3(128, 16), 256, 0, stream>>>(x, Wq, bq, kvg, out);
}

// Round 6
// 689.267 us; speedup vs baseline: 2.0682x; 2.0682x over previous
//
#include <hip/hip_runtime.h>
#include <math.h>

#define BATCH  4
#define SEQ    2048
#define DIMK   2048
#define NHEADS 16
#define DH     128
#define KW     4096    // stored row width: [hi(2048) | lo(2048)]
#define KSTEPS 192     // 3 segments x 64 k-steps of 32

static constexpr float SCALE = 0.088388347648318447f; // 1/sqrt(128)
static constexpr float EPS_N = 1e-12f;

typedef unsigned short u16;
typedef short short8 __attribute__((ext_vector_type(8)));
typedef float fx4 __attribute__((ext_vector_type(4)));

// ---------------------------------------------------------------- helpers
__device__ __forceinline__ u16 bf16_rn(float f) {
    unsigned int u = __float_as_uint(f);
    unsigned int r = u + 0x7FFFu + ((u >> 16) & 1u);
    return (u16)(r >> 16);
}
__device__ __forceinline__ float bf16_to_f(u16 h) {
    return __uint_as_float(((unsigned int)h) << 16);
}
__device__ __forceinline__ void gload16(const void* gsrc, void* ldst) {
    __builtin_amdgcn_global_load_lds(
        (const __attribute__((address_space(1))) unsigned int*)gsrc,
        (__attribute__((address_space(3))) unsigned int*)ldst, 16, 0, 0);
}
__device__ __forceinline__ uint4 pack8(const u16 h[8]) {
    uint4 w;
    w.x = h[0] | ((unsigned int)h[1] << 16);
    w.y = h[2] | ((unsigned int)h[3] << 16);
    w.z = h[4] | ((unsigned int)h[5] << 16);
    w.w = h[6] | ((unsigned int)h[7] << 16);
    return w;
}
// segment k-offsets: A uses [hi,hi,lo], B uses [hi,lo,hi]
__device__ __forceinline__ int segA(int s) { return (s == 2) ? 2048 : 0; }
__device__ __forceinline__ int segB(int s) { return (s == 1) ? 2048 : 0; }

// ---------------------------------------------------------------- fp32 -> bf16 [hi|lo]
__global__ __launch_bounds__(256)
void split_conv(const float* __restrict__ src, u16* __restrict__ dst)
{
    const int r = blockIdx.x, c8 = threadIdx.x;
    const float* s = src + (size_t)r * DIMK + c8 * 8;
    float4 f0 = *(const float4*)s;
    float4 f1 = *(const float4*)(s + 4);
    float f[8] = {f0.x, f0.y, f0.z, f0.w, f1.x, f1.y, f1.z, f1.w};
    u16 hi[8], lo[8];
#pragma unroll
    for (int j = 0; j < 8; ++j) {
        hi[j] = bf16_rn(f[j]);
        lo[j] = bf16_rn(f[j] - bf16_to_f(hi[j]));
    }
    u16* d = dst + (size_t)r * KW + c8 * 8;
    *(uint4*)(d)        = pack8(hi);
    *(uint4*)(d + 2048) = pack8(lo);
}

// ---------------------------------------------------------------- GEMM core pieces
// LDS per buffer: A tile [128][32] bf16 (8KB) then B tile [128][32] (8KB).
// Ag/Bg point at (m-tile base + k-window); row stride KW.
__device__ __forceinline__ void stage_tiles(const u16* __restrict__ Ag,
                                            const u16* __restrict__ Bg,
                                            char* region, int w, int l)
{
#pragma unroll
    for (int i = 0; i < 2; ++i) {
        int c = w * 64 + l + 256 * i;      // 16B-chunk id 0..511
        int row = c >> 2, k16 = c & 3;
        gload16(Ag + (size_t)row * KW + k16 * 8,
                region + w * 1024 + i * 4096);
    }
#pragma unroll
    for (int i = 0; i < 2; ++i) {
        int c = w * 64 + l + 256 * i;
        int row = c >> 2, k16 = c & 3;
        gload16(Bg + (size_t)row * KW + k16 * 8,
                region + 8192 + w * 1024 + i * 4096);
    }
}

__device__ __forceinline__ void compute_step(const char* region,
                                             int wr, int wc, int lg, int lm,
                                             fx4 acc[4][4])
{
    short8 a[4], b[4];
#pragma unroll
    for (int m = 0; m < 4; ++m)
        a[m] = *(const short8*)(region + (wr * 64 + m * 16 + lm) * 64 + lg * 16);
#pragma unroll
    for (int n = 0; n < 4; ++n)
        b[n] = *(const short8*)(region + 8192 + (wc * 64 + n * 16 + lm) * 64 + lg * 16);
#pragma unroll
    for (int m = 0; m < 4; ++m)
#pragma unroll
        for (int n = 0; n < 4; ++n)
            acc[m][n] = __builtin_amdgcn_mfma_f32_16x16x32_bf16(a[m], b[n], acc[m][n], 0, 0, 0);
}

// ---------------------------------------------------------------- K/V projection (MFMA)
__global__ __launch_bounds__(256)
void kv_gemm_kernel(const u16* __restrict__ Ab, const u16* __restrict__ Bb,
                    const float* __restrict__ bk, const float* __restrict__ bv,
                    float* __restrict__ kraw, float* __restrict__ vraw)
{
    __shared__ __align__(16) char smem[32768];
    const int tid = threadIdx.x;
    const int w = tid >> 6, l = tid & 63;
    const int wr = w >> 1, wc = w & 1, lg = l >> 4, lm = l & 15;
    const int m0 = blockIdx.x * 128;
    const u16* Ag = Ab + (size_t)m0 * KW;
    const u16* Bg = Bb + (size_t)(blockIdx.y * 128) * KW;

    fx4 acc[4][4];
#pragma unroll
    for (int m = 0; m < 4; ++m)
#pragma unroll
        for (int n = 0; n < 4; ++n) acc[m][n] = (fx4)0.f;

    stage_tiles(Ag, Bg, smem, w, l);   // ks=0: seg0, kin=0
    __syncthreads();
    int cur = 0;
    for (int ks = 0; ks < KSTEPS; ++ks) {
        int nx = ks + 1;
        if (nx < KSTEPS) {
            int s = nx >> 6, kin = (nx & 63) * 32;
            stage_tiles(Ag + segA(s) + kin, Bg + segB(s) + kin,
                        smem + (cur ^ 1) * 16384, w, l);
        }
        compute_step(smem + cur * 16384, wr, wc, lg, lm, acc);
        __syncthreads();
        cur ^= 1;
    }

    const float* bias = blockIdx.y ? bv : bk;
    float* Y          = blockIdx.y ? vraw : kraw;
    float bb[4];
#pragma unroll
    for (int n = 0; n < 4; ++n) bb[n] = bias[wc * 64 + n * 16 + lm];
#pragma unroll
    for (int m = 0; m < 4; ++m)
#pragma unroll
        for (int n = 0; n < 4; ++n)
#pragma unroll
            for (int j = 0; j < 4; ++j) {
                int row = wr * 64 + m * 16 + lg * 4 + j;
                int col = wc * 64 + n * 16 + lm;
                Y[(size_t)(m0 + row) * DH + col] = acc[m][n][j] + bb[n];
            }
}

// ---------------------------------------------------------------- Q GEMM + norm + xKV
__global__ __launch_bounds__(256)
void q_gemm_kernel(const u16* __restrict__ Ab, const u16* __restrict__ Bb,
                   const float* __restrict__ bq,
                   const u16* __restrict__ kvH, const u16* __restrict__ kvL,
                   float* __restrict__ out)
{
    __shared__ __align__(16) char smem[34816];  // 2x16KB dbuf; reused as qs[128][136] bf16
    __shared__ float rowsq[2][128];
    __shared__ float invn[128];
    const int tid = threadIdx.x;
    const int w = tid >> 6, l = tid & 63;
    const int wr = w >> 1, wc = w & 1, lg = l >> 4, lm = l & 15;
    const int m0 = blockIdx.x * 128, h = blockIdx.y;
    const int batch = blockIdx.x >> 4;
    const u16* Ag = Ab + (size_t)m0 * KW;
    const u16* Bg = Bb + (size_t)(h * 128) * KW;

    fx4 acc[4][4];
#pragma unroll
    for (int m = 0; m < 4; ++m)
#pragma unroll
        for (int n = 0; n < 4; ++n) acc[m][n] = (fx4)0.f;

    stage_tiles(Ag, Bg, smem, w, l);
    __syncthreads();
    int cur = 0;
    for (int ks = 0; ks < KSTEPS; ++ks) {
        int nx = ks + 1;
        if (nx < KSTEPS) {
            int s = nx >> 6, kin = (nx & 63) * 32;
            stage_tiles(Ag + segA(s) + kin, Bg + segB(s) + kin,
                        smem + (cur ^ 1) * 16384, w, l);
        }
        compute_step(smem + cur * 16384, wr, wc, lg, lm, acc);
        __syncthreads();
        cur ^= 1;
    }

    // ---- bias + per-row sum of squares
    float bb[4];
#pragma unroll
    for (int n = 0; n < 4; ++n) bb[n] = bq[h * DH + wc * 64 + n * 16 + lm];
#pragma unroll
    for (int m = 0; m < 4; ++m)
#pragma unroll
        for (int j = 0; j < 4; ++j) {
            float s = 0.f;
#pragma unroll
            for (int n = 0; n < 4; ++n) {
                float v = acc[m][n][j] + bb[n];
                acc[m][n][j] = v;
                s += v * v;
            }
            s += __shfl_xor(s, 1); s += __shfl_xor(s, 2);
            s += __shfl_xor(s, 4); s += __shfl_xor(s, 8);
            if (lm == 0) rowsq[wc][wr * 64 + m * 16 + lg * 4 + j] = s;
        }
    __syncthreads();
    if (tid < 128)
        invn[tid] = 1.f / fmaxf(sqrtf(rowsq[0][tid] + rowsq[1][tid]), EPS_N);
    __syncthreads();

    // ---- normalized q -> bf16 into LDS (overlays dbuf; main loop done)
    u16* qs = (u16*)smem;   // [128][136]
#pragma unroll
    for (int m = 0; m < 4; ++m)
#pragma unroll
        for (int j = 0; j < 4; ++j) {
            int row = wr * 64 + m * 16 + lg * 4 + j;
            float iv = invn[row];
#pragma unroll
            for (int n = 0; n < 4; ++n)
                qs[row * 136 + wc * 64 + n * 16 + lm] = bf16_rn(acc[m][n][j] * iv);
        }
    __syncthreads();

    // ---- PV: out_tile = qn(128x128) @ kv_b(128x128); kv = bf16 hi+lo
    const u16* kH = kvH + (size_t)batch * DH * DH;  // kvT[c][d]
    const u16* kL = kvL + (size_t)batch * DH * DH;
    fx4 acc2[4][4];
#pragma unroll
    for (int m = 0; m < 4; ++m)
#pragma unroll
        for (int n = 0; n < 4; ++n) acc2[m][n] = (fx4)0.f;

#pragma unroll
    for (int d0 = 0; d0 < DH; d0 += 32) {
        short8 a2[4], bh[4], bl[4];
#pragma unroll
        for (int m = 0; m < 4; ++m)
            a2[m] = *(const short8*)&qs[(wr * 64 + m * 16 + lm) * 136 + d0 + lg * 8];
#pragma unroll
        for (int n = 0; n < 4; ++n) {
            int c = wc * 64 + n * 16 + lm;
            bh[n] = *(const short8*)&kH[c * DH + d0 + lg * 8];
            bl[n] = *(const short8*)&kL[c * DH + d0 + lg * 8];
        }
#pragma unroll
        for (int m = 0; m < 4; ++m)
#pragma unroll
            for (int n = 0; n < 4; ++n) {
                acc2[m][n] = __builtin_amdgcn_mfma_f32_16x16x32_bf16(a2[m], bh[n], acc2[m][n], 0, 0, 0);
                acc2[m][n] = __builtin_amdgcn_mfma_f32_16x16x32_bf16(a2[m], bl[n], acc2[m][n], 0, 0, 0);
            }
    }

#pragma unroll
    for (int m = 0; m < 4; ++m)
#pragma unroll
        for (int n = 0; n < 4; ++n)
#pragma unroll
            for (int j = 0; j < 4; ++j) {
                int row = wr * 64 + m * 16 + lg * 4 + j;
                int R = m0 + row;
                int c = wc * 64 + n * 16 + lm;
                out[(((size_t)(R >> 11) * NHEADS + h) * SEQ + (R & 2047)) * DH + c] = acc2[m][n][j];
            }
}

// ---------------------------------------------------------------- kv outer + reduce
__global__ __launch_bounds__(256)
void kv_outer_kernel(const float* __restrict__ kraw,
                     const float* __restrict__ vraw,
                     float* __restrict__ partials)
{
    __shared__ float invn[128];
    __shared__ float kbuf[8][128];
    __shared__ float vbuf[8][128];

    const int tid = threadIdx.x;
    const int bx  = blockIdx.x;
    const int g0  = (bx >> 4) * SEQ + (bx & 15) * 128;

    {
        const int m = tid >> 1, half = tid & 1;
        const float* row = &kraw[(size_t)(g0 + m) * DH + half * 64];
        float s = 0.f;
#pragma unroll
        for (int j = 0; j < 64; j += 4) {
            float4 t4 = *(const float4*)&row[j];
            s += t4.x * t4.x + t4.y * t4.y + t4.z * t4.z + t4.w * t4.w;
        }
        s += __shfl_xor(s, 1);
        if (!half) invn[m] = 1.0f / fmaxf(sqrtf(s), EPS_N);
    }
    __syncthreads();

    const int d1 = tid >> 1;
    const int d2b = (tid & 1) * 64;
    float4 acc[16];
#pragma unroll
    for (int j = 0; j < 16; ++j) acc[j] = make_float4(0.f, 0.f, 0.f, 0.f);

    for (int mc = 0; mc < 128; mc += 8) {
        const int lr = tid >> 5;
        const int lc = (tid & 31) * 4;
        float4 kk = *(const float4*)&kraw[(size_t)(g0 + mc + lr) * DH + lc];
        const float sc = invn[mc + lr];
        kk.x *= sc; kk.y *= sc; kk.z *= sc; kk.w *= sc;
        *(float4*)&kbuf[lr][lc] = kk;
        float4 vv = *(const float4*)&vraw[(size_t)(g0 + mc + lr) * DH + lc];
        *(float4*)&vbuf[lr][lc] = vv;
        __syncthreads();

#pragma unroll
        for (int mm = 0; mm < 8; ++mm) {
            const float kn = kbuf[mm][d1];
#pragma unroll
            for (int j = 0; j < 16; ++j) {
                float4 v4 = *(const float4*)&vbuf[mm][d2b + j * 4];
                acc[j].x = fmaf(kn, v4.x, acc[j].x);
                acc[j].y = fmaf(kn, v4.y, acc[j].y);
                acc[j].z = fmaf(kn, v4.z, acc[j].z);
                acc[j].w = fmaf(kn, v4.w, acc[j].w);
            }
        }
        __syncthreads();
    }

    float* p = &partials[(size_t)bx * 16384 + (size_t)d1 * 128 + d2b];
#pragma unroll
    for (int j = 0; j < 16; ++j) *(float4*)&p[j * 4] = acc[j];
}

// reduce 16 chunk-partials -> kvT (transposed, scaled, bf16 hi/lo)
__global__ __launch_bounds__(256)
void kv_reduce_bf16(const float* __restrict__ partials,
                    u16* __restrict__ kvH, u16* __restrict__ kvL)
{
    const int i = blockIdx.x * 256 + threadIdx.x;  // 0..65535
    const int b = i >> 14;
    const int e = i & 16383;
    const int d = e >> 7, c = e & 127;
    float s = 0.f;
#pragma unroll
    for (int ch = 0; ch < 16; ++ch)
        s += partials[(size_t)(b * 16 + ch) * 16384 + e];
    s *= SCALE;
    u16 hh = bf16_rn(s);
    u16 ll = bf16_rn(s - bf16_to_f(hh));
    kvH[(size_t)b * DH * DH + c * DH + d] = hh;
    kvL[(size_t)b * DH * DH + c * DH + d] = ll;
}

// ================================================================ fallback f32 path
__global__ __launch_bounds__(256)
void kv_proj_kernel(const float* __restrict__ ctx,
                    const float* __restrict__ Wk, const float* __restrict__ bk,
                    const float* __restrict__ Wv, const float* __restrict__ bv,
                    float* __restrict__ kraw, float* __restrict__ vraw)
{
    __shared__ float As[16][72];
    __shared__ float Bs[16][136];

    const int tid = threadIdx.x;
    const int tx = tid & 15, ty = tid >> 4;
    const int m0 = blockIdx.x * 64;

    const float* __restrict__ W    = blockIdx.y ? Wv : Wk;
    const float* __restrict__ bias = blockIdx.y ? bv : bk;
    float* __restrict__ Y          = blockIdx.y ? vraw : kraw;

    const int arow = tid >> 2, ak4 = (tid & 3) << 2;
    const int brow = tid >> 1, bk8 = (tid & 1) << 3;

    float acc[4][8];
#pragma unroll
    for (int i = 0; i < 4; ++i)
#pragma unroll
        for (int j = 0; j < 8; ++j) acc[i][j] = 0.f;

    for (int k0 = 0; k0 < DIMK; k0 += 16) {
        float4 av = *(const float4*)&ctx[(size_t)(m0 + arow) * DIMK + k0 + ak4];
        As[ak4 + 0][arow] = av.x; As[ak4 + 1][arow] = av.y;
        As[ak4 + 2][arow] = av.z; As[ak4 + 3][arow] = av.w;

        float4 b0 = *(const float4*)&W[(size_t)brow * DIMK + k0 + bk8];
        float4 b1 = *(const float4*)&W[(size_t)brow * DIMK + k0 + bk8 + 4];
        Bs[bk8 + 0][brow] = b0.x; Bs[bk8 + 1][brow] = b0.y;
        Bs[bk8 + 2][brow] = b0.z; Bs[bk8 + 3][brow] = b0.w;
        Bs[bk8 + 4][brow] = b1.x; Bs[bk8 + 5][brow] = b1.y;
        Bs[bk8 + 6][brow] = b1.z; Bs[bk8 + 7][brow] = b1.w;
        __syncthreads();

#pragma unroll
        for (int k = 0; k < 16; ++k) {
            float4 a  = *(const float4*)&As[k][ty * 4];
            float4 p  = *(const float4*)&Bs[k][tx * 8];
            float4 q4 = *(const float4*)&Bs[k][tx * 8 + 4];
            float avals[4] = {a.x, a.y, a.z, a.w};
            float bvals[8] = {p.x, p.y, p.z, p.w, q4.x, q4.y, q4.z, q4.w};
#pragma unroll
            for (int i = 0; i < 4; ++i)
#pragma unroll
                for (int j = 0; j < 8; ++j)
                    acc[i][j] = fmaf(avals[i], bvals[j], acc[i][j]);
        }
        __syncthreads();
    }

    float bb[8];
#pragma unroll
    for (int j = 0; j < 8; ++j) bb[j] = bias[tx * 8 + j];

#pragma unroll
    for (int i = 0; i < 4; ++i) {
        const int r = m0 + ty * 4 + i;
        float4 o0, o1;
        o0.x = acc[i][0] + bb[0]; o0.y = acc[i][1] + bb[1];
        o0.z = acc[i][2] + bb[2]; o0.w = acc[i][3] + bb[3];
        o1.x = acc[i][4] + bb[4]; o1.y = acc[i][5] + bb[5];
        o1.z = acc[i][6] + bb[6]; o1.w = acc[i][7] + bb[7];
        *(float4*)&Y[(size_t)r * DH + tx * 8]     = o0;
        *(float4*)&Y[(size_t)r * DH + tx * 8 + 4] = o1;
    }
}

__global__ __launch_bounds__(256)
void kv_reduce_kernel(const float* __restrict__ partials, float* __restrict__ kvg)
{
    const int i = blockIdx.x * 256 + threadIdx.x;
    const int b = i >> 14;
    const int e = i & 16383;
    float s = 0.f;
#pragma unroll
    for (int c = 0; c < 16; ++c)
        s += partials[(size_t)(b * 16 + c) * 16384 + e];
    kvg[i] = s * SCALE;
}

__global__ __launch_bounds__(256)
void q_out_kernel(const float* __restrict__ x,
                  const float* __restrict__ Wq, const float* __restrict__ bq,
                  const float* __restrict__ kvg, float* __restrict__ out)
{
    __shared__ float As[16][72];
    __shared__ float Bs[16][136];
    __shared__ float qs[64][136];

    const int tid = threadIdx.x;
    const int tx = tid & 15, ty = tid >> 4;
    const int m0 = blockIdx.x * 64;
    const int h  = blockIdx.y;
    const int n0 = h * DH;

    const int arow = tid >> 2, ak4 = (tid & 3) << 2;
    const int brow = tid >> 1, bk8 = (tid & 1) << 3;

    float acc[4][8];
#pragma unroll
    for (int i = 0; i < 4; ++i)
#pragma unroll
        for (int j = 0; j < 8; ++j) acc[i][j] = 0.f;

    for (int k0 = 0; k0 < DIMK; k0 += 16) {
        float4 av = *(const float4*)&x[(size_t)(m0 + arow) * DIMK + k0 + ak4];
        As[ak4 + 0][arow] = av.x; As[ak4 + 1][arow] = av.y;
        As[ak4 + 2][arow] = av.z; As[ak4 + 3][arow] = av.w;

        float4 b0 = *(const float4*)&Wq[(size_t)(n0 + brow) * DIMK + k0 + bk8];
        float4 b1 = *(const float4*)&Wq[(size_t)(n0 + brow) * DIMK + k0 + bk8 + 4];
        Bs[bk8 + 0][brow] = b0.x; Bs[bk8 + 1][brow] = b0.y;
        Bs[bk8 + 2][brow] = b0.z; Bs[bk8 + 3][brow] = b0.w;
        Bs[bk8 + 4][brow] = b1.x; Bs[bk8 + 5][brow] = b1.y;
        Bs[bk8 + 6][brow] = b1.z; Bs[bk8 + 7][brow] = b1.w;
        __syncthreads();

#pragma unroll
        for (int k = 0; k < 16; ++k) {
            float4 a  = *(const float4*)&As[k][ty * 4];
            float4 p  = *(const float4*)&Bs[k][tx * 8];
            float4 q4 = *(const float4*)&Bs[k][tx * 8 + 4];
            float avals[4] = {a.x, a.y, a.z, a.w};
            float bvals[8] = {p.x, p.y, p.z, p.w, q4.x, q4.y, q4.z, q4.w};
#pragma unroll
            for (int i = 0; i < 4; ++i)
#pragma unroll
                for (int j = 0; j < 8; ++j)
                    acc[i][j] = fmaf(avals[i], bvals[j], acc[i][j]);
        }
        __syncthreads();
    }

    float bb[8];
#pragma unroll
    for (int j = 0; j < 8; ++j) bb[j] = bq[n0 + tx * 8 + j];

    float inv[4];
#pragma unroll
    for (int i = 0; i < 4; ++i) {
        float s = 0.f;
#pragma unroll
        for (int j = 0; j < 8; ++j) {
            acc[i][j] += bb[j];
            s += acc[i][j] * acc[i][j];
        }
        s += __shfl_xor(s, 1);
        s += __shfl_xor(s, 2);
        s += __shfl_xor(s, 4);
        s += __shfl_xor(s, 8);
        inv[i] = 1.0f / fmaxf(sqrtf(s), EPS_N);
    }

#pragma unroll
    for (int i = 0; i < 4; ++i)
#pragma unroll
        for (int j = 0; j < 8; ++j)
            qs[ty * 4 + i][tx * 8 + j] = acc[i][j] * inv[i];
    __syncthreads();

    const int b = m0 / SEQ;
    const float* __restrict__ kvb = kvg + (size_t)b * DH * DH;

    float acc2[4][8];
#pragma unroll
    for (int i = 0; i < 4; ++i)
#pragma unroll
        for (int j = 0; j < 8; ++j) acc2[i][j] = 0.f;

    for (int dt = 0; dt < DH; dt += 16) {
        const int drow = tid >> 4;
        const int dcol = (tid & 15) * 8;
        float4 c0 = *(const float4*)&kvb[(size_t)(dt + drow) * DH + dcol];
        float4 c1 = *(const float4*)&kvb[(size_t)(dt + drow) * DH + dcol + 4];
        __syncthreads();
        *(float4*)&Bs[drow][dcol]     = c0;
        *(float4*)&Bs[drow][dcol + 4] = c1;
        __syncthreads();

#pragma unroll
        for (int d = 0; d < 16; ++d) {
            float qv[4];
#pragma unroll
            for (int i = 0; i < 4; ++i) qv[i] = qs[ty * 4 + i][dt + d];
            float4 p  = *(const float4*)&Bs[d][tx * 8];
            float4 q4 = *(const float4*)&Bs[d][tx * 8 + 4];
            float bvals[8] = {p.x, p.y, p.z, p.w, q4.x, q4.y, q4.z, q4.w};
#pragma unroll
            for (int i = 0; i < 4; ++i)
#pragma unroll
                for (int j = 0; j < 8; ++j)
                    acc2[i][j] = fmaf(qv[i], bvals[j], acc2[i][j]);
        }
    }

#pragma unroll
    for (int i = 0; i < 4; ++i) {
        const int r    = m0 + ty * 4 + i;
        const int iseq = r - b * SEQ;
        float4 o0, o1;
        o0.x = acc2[i][0]; o0.y = acc2[i][1]; o0.z = acc2[i][2]; o0.w = acc2[i][3];
        o1.x = acc2[i][4]; o1.y = acc2[i][5]; o1.z = acc2[i][6]; o1.w = acc2[i][7];
        const size_t obase = (((size_t)b * NHEADS + h) * SEQ + iseq) * DH + tx * 8;
        *(float4*)&out[obase]     = o0;
        *(float4*)&out[obase + 4] = o1;
    }
}

// ================================================================ launch
extern "C" void kernel_launch(void* const* d_in, const int* in_sizes, int n_in,
                              void* d_out, int out_size, void* d_ws, size_t ws_size,
                              hipStream_t stream)
{
    const float* x   = (const float*)d_in[0];
    const float* ctx = (const float*)d_in[1];
    const float* Wq  = (const float*)d_in[2];
    const float* bq  = (const float*)d_in[3];
    const float* Wk  = (const float*)d_in[4];
    const float* bk  = (const float*)d_in[5];
    const float* Wv  = (const float*)d_in[6];
    const float* bv  = (const float*)d_in[7];

    float* out      = (float*)d_out;
    float* kraw     = out;              // 8192x128 f32
    float* vraw     = out + 1048576;
    float* partials = out + 2097152;    // 64 x 16384 f32

    const size_t SZ_BIG  = (size_t)8192 * KW * 2;   // 67,108,864
    const size_t SZ_WQ   = (size_t)2048 * KW * 2;   // 16,777,216
    const size_t SZ_WKV  = (size_t)256  * KW * 2;   //  2,097,152
    const size_t SZ_KV   = (size_t)2 * BATCH * DH * DH * 2; // 262,144
    const size_t NEED = SZ_BIG + SZ_WQ + SZ_WKV + SZ_KV;    // ~86.2 MB

    if (ws_size >= NEED) {
        char* ws  = (char*)d_ws;
        u16* big  = (u16*)ws;
        u16* WqS  = (u16*)(ws + SZ_BIG);
        u16* WkvS = (u16*)(ws + SZ_BIG + SZ_WQ);
        u16* kvH  = (u16*)(ws + SZ_BIG + SZ_WQ + SZ_WKV);
        u16* kvL  = kvH + (size_t)BATCH * DH * DH;

        split_conv<<<8192, 256, 0, stream>>>(ctx, big);
        split_conv<<<128, 256, 0, stream>>>(Wk, WkvS);
        split_conv<<<128, 256, 0, stream>>>(Wv, WkvS + (size_t)128 * KW);
        kv_gemm_kernel<<<dim3(64, 2), 256, 0, stream>>>(big, WkvS, bk, bv, kraw, vraw);
        kv_outer_kernel<<<64, 256, 0, stream>>>(kraw, vraw, partials);
        kv_reduce_bf16<<<256, 256, 0, stream>>>(partials, kvH, kvL);
        split_conv<<<8192, 256, 0, stream>>>(x, big);
        split_conv<<<2048, 256, 0, stream>>>(Wq, WqS);
        q_gemm_kernel<<<dim3(64, 16), 256, 0, stream>>>(big, WqS, bq, kvH, kvL, out);
    } else {
        float* kvg = (float*)d_ws;  // 256 KB
        kv_proj_kernel<<<dim3(128, 2), 256, 0, stream>>>(ctx, Wk, bk, Wv, bv, kraw, vraw);
        kv_outer_kernel<<<64, 256, 0, stream>>>(kraw, vraw, partials);
        kv_reduce_kernel<<<256, 256, 0, stream>>>(partials, kvg);
        q_out_kernel<<<dim3(128, 16), 256, 0, stream>>>(x, Wq, bq, kvg, out);
    }
}